// Round 10
// baseline (183.929 us; speedup 1.0000x reference)
//
#include <hip/hip_runtime.h>
#include <math.h>

// Problem constants (GroupedKANLayer): B=2, C=31, D=7, H=W=192
#define NBATCH 2
#define NC 31
#define ND 7
#define NH 192
#define NW 192
#define HW (NH * NW)            // 36864
#define NP (NBATCH * HW)        // 73728 pixels
#define NBASIS 8
#define CLEN 56                 // ND * NBASIS
#define KP 70                   // CLEN + ND + ND

// MFMA conv geometry
#define KK 288                  // K padded (31*9 = 279 -> 288 = 9 chunks of 32)
#define KCHUNKS 9
#define MT 5                    // m-tiles of 16 (80 ocs, 70 real)
#define NFRAG (MT * KCHUNKS)    // 45 A-fragments
#define BSTR 149                // B_lds row stride in WORDS (odd -> 2/bank writes)

// kan tiling: 64 pixels per block, channel-pair ILP
#define KPPB 64

typedef __attribute__((ext_vector_type(8))) short short8;   // 8 bf16 = 4 VGPRs
typedef __attribute__((ext_vector_type(4))) float float4v;

union FragU { uint4 u; short8 s; };

__device__ __forceinline__ unsigned short f2bf(float f)
{
    unsigned u = __float_as_uint(f);
    unsigned r = (u + 0x7FFFu + ((u >> 16) & 1u)) >> 16;   // RNE
    return (unsigned short)r;
}

// ---------------------------------------------------------------------------
// Kernel 1: ctx = mean_d x, float4-vectorized.
// ---------------------------------------------------------------------------
__global__ __launch_bounds__(256) void ctx_mean_kernel(
    const float4* __restrict__ x4, float4* __restrict__ ctx4)
{
    const int HW4 = HW / 4;
    int idx = blockIdx.x * 256 + threadIdx.x;
    if (idx >= NBATCH * NC * HW4) return;
    int hw4 = idx % HW4;
    int bc  = idx / HW4;
    const float4* src = x4 + (size_t)bc * (ND * HW4) + hw4;
    float4 a = src[0];
#pragma unroll
    for (int d = 1; d < ND; ++d) {
        float4 v = src[d * HW4];
        a.x += v.x; a.y += v.y; a.z += v.z; a.w += v.w;
    }
    const float inv = 1.0f / 7.0f;
    a.x *= inv; a.y *= inv; a.z *= inv; a.w *= inv;
    ctx4[idx] = a;
}

// ---------------------------------------------------------------------------
// Kernel 2a: pack gen_w into A-fragment order (bf16) in global ws.
// Frag f = m*9 + chunk; lane holds A[oc = m*16 + (lane&15)]
// [k = chunk*32 + (lane>>4)*8 + j], j=0..7, padded with 0 (k>=279 or oc>=70).
// k -> (ic, tau): ic = (k*456)>>12 (exact for k<290), tau = k - 9*ic.
// ---------------------------------------------------------------------------
__global__ __launch_bounds__(256) void prep_weights(
    const float* __restrict__ gw, uint4* __restrict__ aws)
{
    int t = blockIdx.x * 256 + threadIdx.x;
    if (t >= NFRAG * 64) return;
    int f    = t >> 6;
    int lane = t & 63;
    int m     = f / KCHUNKS;
    int chunk = f - m * KCHUNKS;
    int oc    = m * 16 + (lane & 15);
    int kbase = chunk * 32 + (lane >> 4) * 8;

    unsigned short v[8];
#pragma unroll
    for (int j = 0; j < 8; ++j) {
        int k  = kbase + j;
        int ic = (k * 456) >> 12;
        int tau = k - 9 * ic;
        float val = 0.f;
        if (k < 279 && oc < KP)
            val = gw[(oc * NC + ic) * 9 + tau];
        v[j] = f2bf(val);
    }
    uint4 q;
    q.x = (unsigned)v[0] | ((unsigned)v[1] << 16);
    q.y = (unsigned)v[2] | ((unsigned)v[3] << 16);
    q.z = (unsigned)v[4] | ((unsigned)v[5] << 16);
    q.w = (unsigned)v[6] | ((unsigned)v[7] << 16);
    aws[t] = q;
}

// ---------------------------------------------------------------------------
// Kernel 2b: conv as implicit GEMM via MFMA bf16.
// Block = 256 threads = 4 waves, owns 64 consecutive pixels of one row.
// Build phase: im2col B in LDS bf16 [n=64][K=288], row stride 149 words;
//   thread t: n = t&63 (coalesced global ctx reads), k-range (t>>6)*72..+71,
//   36 packed ushort2 (b32) writes -> banks n*21 mod 32 = exactly 2/bank.
// MFMA phase: wave wv -> 16-px column; 9 chunks x 5 m-tiles MFMA;
//   A-frags from global aws (coalesced dwordx4, L2-resident);
//   B-frags: 4x ds_read_b32 each. D: oc = m*16+(lane>>4)*4+r, px = lane&15.
// grid = NP/64 = 1152 blocks.
// ---------------------------------------------------------------------------
__global__ __launch_bounds__(256, 4) void conv_mfma(
    const float* __restrict__ ctx, const uint4* __restrict__ aws,
    const float* __restrict__ gb, float* __restrict__ wts)
{
    __shared__ unsigned short Blds[64 * 2 * BSTR];   // 64 rows * 149 words = 38144 B

    const int t  = threadIdx.x;
    const int p0 = blockIdx.x * 64;
    const int b  = p0 / HW;
    const int hw0 = p0 - b * HW;
    const int h  = hw0 / NW;
    const int w0 = hw0 - h * NW;

    // ---- build im2col B ----
    {
        const int n  = t & 63;
        const int kg = t >> 6;                 // k-range [kg*72, kg*72+72)
        const float* cbase = ctx + (b * NC) * HW;
        unsigned* BW = (unsigned*)Blds;
#pragma unroll
        for (int j = 0; j < 36; ++j) {
            int k0 = kg * 72 + 2 * j;
            unsigned short e[2];
#pragma unroll
            for (int q = 0; q < 2; ++q) {
                int k  = k0 + q;
                int ic = (k * 456) >> 12;
                int tau = k - 9 * ic;
                int dr = (tau * 11) >> 5;
                int dc = tau - 3 * dr;
                int gh = h + dr - 1;
                int gc = w0 + n + dc - 1;
                bool ok = (k < 279) && (gh >= 0) && (gh < NH) && (gc >= 0) && (gc < NW);
                int icc = min(ic, NC - 1);
                int ghc = min(max(gh, 0), NH - 1);
                int gcc = min(max(gc, 0), NW - 1);
                float val = cbase[icc * HW + ghc * NW + gcc];
                e[q] = ok ? f2bf(val) : (unsigned short)0;
            }
            BW[n * BSTR + (k0 >> 1)] = (unsigned)e[0] | ((unsigned)e[1] << 16);
        }
    }
    __syncthreads();

    // ---- MFMA phase ----
    const int lane = t & 63;
    const int wv   = t >> 6;
    const int nl   = lane & 15;
    const int g    = lane >> 4;
    const int nloc = wv * 16 + nl;

    float4v acc[MT];
#pragma unroll
    for (int m = 0; m < MT; ++m) acc[m] = (float4v){0.f, 0.f, 0.f, 0.f};

    const unsigned* BW = (const unsigned*)Blds;

#pragma unroll
    for (int chunk = 0; chunk < KCHUNKS; ++chunk) {
        int wbase = nloc * BSTR + chunk * 16 + g * 4;
        FragU bf;
        bf.u.x = BW[wbase + 0];
        bf.u.y = BW[wbase + 1];
        bf.u.z = BW[wbase + 2];
        bf.u.w = BW[wbase + 3];
#pragma unroll
        for (int m = 0; m < MT; ++m) {
            FragU af;
            af.u = aws[(m * KCHUNKS + chunk) * 64 + lane];
            acc[m] = __builtin_amdgcn_mfma_f32_16x16x32_bf16(af.s, bf.s, acc[m], 0, 0, 0);
        }
    }

    // ---- store: wts[oc][p] = acc + bias ----
    const int colp = p0 + nloc;
#pragma unroll
    for (int m = 0; m < MT; ++m) {
#pragma unroll
        for (int r = 0; r < 4; ++r) {
            int oc = m * 16 + g * 4 + r;
            if (oc < KP)
                wts[(size_t)oc * NP + colp] = acc[m][r] + gb[oc];
        }
    }
}

// ---------------------------------------------------------------------------
// kan helpers
// ---------------------------------------------------------------------------
__device__ __forceinline__ float spline_part(float xv, const float* cb, int d)
{
    // cardinal cubic B-spline on uniform knots; cb = scoef + lane,
    // coef gather at LDS stride 64 words (bank = lane%32, 2-way = free)
    float t = (xv + 2.2f) * 2.5f;
    float fi = floorf(t);
    int i = (int)fi;
    float u = t - fi;
    float u2 = u * u, u3 = u2 * u;
    float um = 1.f - u;
    float w0 = um * um * um * (1.f / 6.f);
    float w3 = u3 * (1.f / 6.f);
    float w1 = (3.f * u3 - 6.f * u2 + 4.f) * (1.f / 6.f);
    float w2 = 1.f - w0 - w1 - w3;          // partition of unity
    int j0 = i - 3;
    float sd = 0.f;
#pragma unroll
    for (int k = 0; k < 4; ++k) {
        int j = j0 + k;
        bool valid = (j >= 0) && (j <= 7);
        int jc = valid ? j : 0;
        float wk = (k == 0) ? w0 : (k == 1) ? w1 : (k == 2) ? w2 : w3;
        float cf = cb[(d * NBASIS + jc) * KPPB];
        sd += (valid ? wk : 0.f) * cf;
    }
    return sd;
}

__device__ __forceinline__ float silu(float xv)
{
    return xv / (1.f + __expf(-xv));
}

// ---------------------------------------------------------------------------
// Kernel 3: block = 64 pixels, 4 waves. All 70 wts rows staged to LDS
// [k][64] via b32 (2/bank = free). Wave wv processes 8 channels as 4 pairs
// (two independent spline chains per d). Wave 3 covers channels 23..30
// (ch 23 duplicated by waves 2&3 -> identical value, benign).
// grid = 1152 blocks.
// ---------------------------------------------------------------------------
__global__ __launch_bounds__(256, 3) void kan_kernel(
    const float* __restrict__ x, const float* __restrict__ wts,
    float* __restrict__ out)
{
    __shared__ float scoef[KP * KPPB];   // 70*64*4 = 17920 B
    const int tid = threadIdx.x;
    const int p0  = blockIdx.x * KPPB;

    for (int f = tid; f < KP * KPPB; f += 256)
        scoef[f] = wts[(size_t)(f >> 6) * NP + p0 + (f & 63)];

    __syncthreads();

    const int lane = tid & 63;
    const int wv   = tid >> 6;
    const int p    = p0 + lane;
    const int b    = p / HW;              // uniform (HW % 64 == 0)
    const int hw   = p - b * HW;

    const float* cb64 = scoef + lane;

    float uw[ND], rw[ND];
#pragma unroll
    for (int d = 0; d < ND; ++d) uw[d] = cb64[(CLEN + d) * KPPB];
#pragma unroll
    for (int d = 0; d < ND; ++d) rw[d] = cb64[(CLEN + ND + d) * KPPB];

    const float* xb = x + (size_t)(b * NC) * (ND * HW) + hw;
    float* ob = out + (b * NC) * HW + hw;

    const int c_begin = (wv == 3) ? 23 : wv * 8;   // 8 channels per wave

#pragma unroll
    for (int i = 0; i < 4; ++i) {
        const int c0 = c_begin + 2 * i;
        const int c1 = c0 + 1;
        const float* x0 = xb + (size_t)c0 * ND * HW;
        const float* x1 = xb + (size_t)c1 * ND * HW;
        float s0 = 0.f, s1 = 0.f;
#pragma unroll
        for (int d = 0; d < ND; ++d) {
            float xv0 = x0[d * HW];
            float xv1 = x1[d * HW];
            s0 += uw[d] * spline_part(xv0, cb64, d) + rw[d] * silu(xv0);
            s1 += uw[d] * spline_part(xv1, cb64, d) + rw[d] * silu(xv1);
        }
        ob[c0 * HW] = s0;
        ob[c1 * HW] = s1;
    }
}

// ---------------------------------------------------------------------------
extern "C" void kernel_launch(void* const* d_in, const int* in_sizes, int n_in,
                              void* d_out, int out_size, void* d_ws, size_t ws_size,
                              hipStream_t stream)
{
    const float* x  = (const float*)d_in[0];   // (2,31,7,192,192)
    const float* gw = (const float*)d_in[1];   // (70,31,3,3)
    const float* gb = (const float*)d_in[2];   // (70,)
    float* out = (float*)d_out;                // (2,31,192,192)

    float* ctx = (float*)d_ws;                             // 9.1 MB
    float* wts = ctx + (size_t)NBATCH * NC * HW;           // 20.6 MB
    uint4* aws = (uint4*)(wts + (size_t)KP * NP);          // 45 KB, 16B-aligned

    int n4 = NBATCH * NC * (HW / 4);
    ctx_mean_kernel<<<dim3((n4 + 255) / 256), 256, 0, stream>>>(
        (const float4*)x, (float4*)ctx);
    prep_weights<<<dim3((NFRAG * 64 + 255) / 256), 256, 0, stream>>>(gw, aws);
    conv_mfma<<<dim3(NP / 64), 256, 0, stream>>>(ctx, aws, gb, wts);
    kan_kernel<<<dim3(NP / KPPB), 256, 0, stream>>>(x, wts, out);
}